// Round 2
// baseline (1640.207 us; speedup 1.0000x reference)
//
#include <hip/hip_runtime.h>
#include <hip/hip_bf16.h>
#include <cstdint>

#define DEVI __device__ __forceinline__

typedef __attribute__((ext_vector_type(8))) short short8;
typedef __attribute__((ext_vector_type(4))) float f32x4;
typedef unsigned int u32;
typedef unsigned short u16;

DEVI u16 f2bf(float f) {
  __hip_bfloat16 h = __float2bfloat16(f);
  return *reinterpret_cast<u16*>(&h);
}
DEVI float bf2f_lo(u32 u) { return __uint_as_float(u << 16); }
DEVI float bf2f_hi(u32 u) { return __uint_as_float(u & 0xffff0000u); }

// async global->LDS, 16B per lane. LDS dest must be wave-uniform base + lane*16.
DEVI void async_cp16(const __hip_bfloat16* g, __hip_bfloat16* l) {
  __builtin_amdgcn_global_load_lds(
      (const __attribute__((address_space(1))) u32*)(uintptr_t)g,
      (__attribute__((address_space(3))) u32*)(uintptr_t)l, 16, 0, 0);
}

// ---------------------------------------------------------------------------
// Generic TN GEMM: Z[n][m] = alpha * (sum_k A[m][k]*B[n][k] + bias) + resid
// A: M x K (K contiguous, lda), B: N x K (ldb). bf16. Tile 128x128, BK=32.
// Z addr = n*ldz + m. BIAS_MODE: 0 none, 1 per-M, 2 per-N.
// Split-K: blockIdx.z = batch*nsplit + s; k-window = [s*K, (s+1)*K).
// ATOMIC: Z is fp32, accumulate with atomicAdd (caller zero-fills first).
// ---------------------------------------------------------------------------
template<int BIAS_MODE, bool RESID, bool OUT_BF16, bool ATOMIC>
__global__ __launch_bounds__(256) void gemm_tn(
    const __hip_bfloat16* __restrict__ A, int lda, size_t sA,
    const __hip_bfloat16* __restrict__ B, int ldb, size_t sB,
    void* __restrict__ Zv, int ldz, size_t sZ,
    const float* __restrict__ bias,
    const float* __restrict__ resid, size_t sR,
    float alpha, int K, int nsplit)
{
  __shared__ __hip_bfloat16 lsA[128 * 32];
  __shared__ __hip_bfloat16 lsB[128 * 32];
  const int t    = threadIdx.x;
  const int bz   = blockIdx.z;
  const int bb   = bz / nsplit;          // batch index
  const int sp   = bz - bb * nsplit;     // split index
  const size_t koff = (size_t)sp * K;
  const int n0   = blockIdx.x * 128;
  const int m0   = blockIdx.y * 128;
  const __hip_bfloat16* Ab = A + (size_t)bb * sA + koff;
  const __hip_bfloat16* Bb = B + (size_t)bb * sB + koff;

  const int lane = t & 63;
  const int quad = lane >> 4;
  const int l16  = lane & 15;
  const int wave = t >> 6;
  const int wm   = (wave >> 1) * 64;
  const int wn   = (wave & 1) * 64;

  const int rowc = t >> 2;
  const int kc   = (t & 3) * 8;
  const __hip_bfloat16* ga0 = Ab + (size_t)(m0 + rowc) * lda + kc;
  const __hip_bfloat16* ga1 = Ab + (size_t)(m0 + rowc + 64) * lda + kc;
  const __hip_bfloat16* gb0 = Bb + (size_t)(n0 + rowc) * ldb + kc;
  const __hip_bfloat16* gb1 = Bb + (size_t)(n0 + rowc + 64) * ldb + kc;
  __hip_bfloat16* la0 = lsA + t * 8;
  __hip_bfloat16* la1 = lsA + 2048 + t * 8;
  __hip_bfloat16* lb0 = lsB + t * 8;
  __hip_bfloat16* lb1 = lsB + 2048 + t * 8;

  f32x4 acc[4][4] = {};

  for (int k0 = 0; k0 < K; k0 += 32) {
    __syncthreads();
    async_cp16(ga0, la0);
    async_cp16(ga1, la1);
    async_cp16(gb0, lb0);
    async_cp16(gb1, lb1);
    ga0 += 32; ga1 += 32; gb0 += 32; gb1 += 32;
    __syncthreads();

    short8 af[4], bf[4];
#pragma unroll
    for (int i = 0; i < 4; ++i)
      af[i] = *(const short8*)(lsA + (wm + i * 16 + l16) * 32 + quad * 8);
#pragma unroll
    for (int j = 0; j < 4; ++j)
      bf[j] = *(const short8*)(lsB + (wn + j * 16 + l16) * 32 + quad * 8);
#pragma unroll
    for (int i = 0; i < 4; ++i)
#pragma unroll
      for (int j = 0; j < 4; ++j)
        acc[i][j] = __builtin_amdgcn_mfma_f32_16x16x32_bf16(af[i], bf[j], acc[i][j], 0, 0, 0);
  }

#pragma unroll
  for (int i = 0; i < 4; ++i) {
#pragma unroll
    for (int j = 0; j < 4; ++j) {
      const int m = m0 + wm + i * 16 + quad * 4;
      const int n = n0 + wn + j * 16 + l16;
      f32x4 v = acc[i][j];
      if (BIAS_MODE == 1) v += *(const f32x4*)(bias + m);
      else if (BIAS_MODE == 2) v += bias[n];
      v *= alpha;
      const size_t zoff = (size_t)n * ldz + m;
      if (RESID) v += *(const f32x4*)(resid + (size_t)bb * sR + zoff);
      if (ATOMIC) {
        float* zp = (float*)Zv + (size_t)bb * sZ + zoff;
        atomicAdd(zp + 0, v[0]);
        atomicAdd(zp + 1, v[1]);
        atomicAdd(zp + 2, v[2]);
        atomicAdd(zp + 3, v[3]);
      } else if (OUT_BF16) {
        union { u16 s[4]; uint2 q; } pk;
        pk.s[0] = f2bf(v[0]); pk.s[1] = f2bf(v[1]);
        pk.s[2] = f2bf(v[2]); pk.s[3] = f2bf(v[3]);
        *(uint2*)((__hip_bfloat16*)Zv + (size_t)bb * sZ + zoff) = pk.q;
      } else {
        *(f32x4*)((float*)Zv + (size_t)bb * sZ + zoff) = v;
      }
    }
  }
}

// ---------------------------------------------------------------------------
__global__ __launch_bounds__(256) void gn_stats(const float* __restrict__ x,
                                                float2* __restrict__ stats) {
  const int bg = blockIdx.x;
  const f32x4* p = (const f32x4*)(x + (size_t)bg * 65536);
  float s = 0.f, s2 = 0.f;
  for (int i = threadIdx.x; i < 16384; i += 256) {
    f32x4 v = p[i];
    s  += v[0] + v[1] + v[2] + v[3];
    s2 += v[0]*v[0] + v[1]*v[1] + v[2]*v[2] + v[3]*v[3];
  }
  for (int o = 32; o > 0; o >>= 1) { s += __shfl_down(s, o); s2 += __shfl_down(s2, o); }
  __shared__ float ws[4], ws2[4];
  const int wave = threadIdx.x >> 6;
  if ((threadIdx.x & 63) == 0) { ws[wave] = s; ws2[wave] = s2; }
  __syncthreads();
  if (threadIdx.x == 0) {
    float S  = ws[0] + ws[1] + ws[2] + ws[3];
    float S2 = ws2[0] + ws2[1] + ws2[2] + ws2[3];
    float mu = S * (1.f / 65536.f);
    float var = S2 * (1.f / 65536.f) - mu * mu;
    stats[bg] = make_float2(mu, rsqrtf(var + 1e-6f));
  }
}

// GroupNorm apply + transpose: x[b][c][n] fp32 -> r_t[b][n][c] bf16.
__global__ __launch_bounds__(256) void gn_apply(const float* __restrict__ x,
                                                const float2* __restrict__ stats,
                                                const float* __restrict__ gamma,
                                                const float* __restrict__ beta,
                                                __hip_bfloat16* __restrict__ rt) {
  const int b = blockIdx.y, n0 = blockIdx.x * 64;
  __shared__ float tile[64][65];
  const int t  = threadIdx.x;
  const int cl = t >> 2;
  const int q4 = (t & 3) * 4;
  for (int cc = 0; cc < 8; ++cc) {
    const int c = cc * 64 + cl;
    const float2 ms = stats[b * 32 + (c >> 4)];
    const float ga = gamma[c] * ms.y;
    const float be = beta[c] - ms.x * ga;
    const float* src = x + ((size_t)b * 512 + c) * 4096 + n0;
#pragma unroll
    for (int p = 0; p < 4; ++p) {
      f32x4 v = *(const f32x4*)(src + q4 + p * 16);
      tile[cl][q4 + p * 16 + 0] = fmaf(v[0], ga, be);
      tile[cl][q4 + p * 16 + 1] = fmaf(v[1], ga, be);
      tile[cl][q4 + p * 16 + 2] = fmaf(v[2], ga, be);
      tile[cl][q4 + p * 16 + 3] = fmaf(v[3], ga, be);
    }
    __syncthreads();
    const int nw = t >> 2;
    const int cw = (t & 3) * 16;
    union { u16 s[16]; uint4 q[2]; } pk;
#pragma unroll
    for (int j = 0; j < 16; ++j) pk.s[j] = f2bf(tile[cw + j][nw]);
    __hip_bfloat16* dst = rt + ((size_t)b * 4096 + n0 + nw) * 512 + cc * 64 + cw;
    *(uint4*)dst = pk.q[0];
    *((uint4*)dst + 1) = pk.q[1];
    __syncthreads();
  }
}

// Row softmax, in place, bf16 storage / fp32 math. One block per 4096-row.
__global__ __launch_bounds__(256) void softmax_rows(__hip_bfloat16* __restrict__ a) {
  __hip_bfloat16* p = a + (size_t)blockIdx.x * 4096;
  const int t = threadIdx.x;
  uint4 r0 = *(uint4*)(p + t * 16);
  uint4 r1 = *(uint4*)(p + t * 16 + 8);
  float v[16];
  v[0]=bf2f_lo(r0.x); v[1]=bf2f_hi(r0.x); v[2]=bf2f_lo(r0.y); v[3]=bf2f_hi(r0.y);
  v[4]=bf2f_lo(r0.z); v[5]=bf2f_hi(r0.z); v[6]=bf2f_lo(r0.w); v[7]=bf2f_hi(r0.w);
  v[8]=bf2f_lo(r1.x); v[9]=bf2f_hi(r1.x); v[10]=bf2f_lo(r1.y); v[11]=bf2f_hi(r1.y);
  v[12]=bf2f_lo(r1.z); v[13]=bf2f_hi(r1.z); v[14]=bf2f_lo(r1.w); v[15]=bf2f_hi(r1.w);

  __shared__ float red[4];
  const int wave = t >> 6, lane = t & 63;

  float mx = v[0];
#pragma unroll
  for (int i = 1; i < 16; ++i) mx = fmaxf(mx, v[i]);
  for (int o = 32; o > 0; o >>= 1) mx = fmaxf(mx, __shfl_down(mx, o));
  if (lane == 0) red[wave] = mx;
  __syncthreads();
  mx = fmaxf(fmaxf(red[0], red[1]), fmaxf(red[2], red[3]));
  __syncthreads();

  float sum = 0.f;
#pragma unroll
  for (int i = 0; i < 16; ++i) { v[i] = __expf(v[i] - mx); sum += v[i]; }
  for (int o = 32; o > 0; o >>= 1) sum += __shfl_down(sum, o);
  if (lane == 0) red[wave] = sum;
  __syncthreads();
  sum = red[0] + red[1] + red[2] + red[3];
  const float inv = 1.f / sum;

  union { u16 s[16]; uint4 q[2]; } pk;
#pragma unroll
  for (int i = 0; i < 16; ++i) pk.s[i] = f2bf(v[i] * inv);
  *(uint4*)(p + t * 16) = pk.q[0];
  *(uint4*)(p + t * 16 + 8) = pk.q[1];
}

__global__ __launch_bounds__(256) void cvt_bf16(const float* __restrict__ s,
                                                __hip_bfloat16* __restrict__ d, int n) {
  const int i = (blockIdx.x * 256 + threadIdx.x) * 4;
  if (i < n) {
    f32x4 v = *(const f32x4*)(s + i);
    union { u16 s4[4]; uint2 q; } pk;
    pk.s4[0] = f2bf(v[0]); pk.s4[1] = f2bf(v[1]);
    pk.s4[2] = f2bf(v[2]); pk.s4[3] = f2bf(v[3]);
    *(uint2*)(d + i) = pk.q;
  }
}

__global__ __launch_bounds__(256) void pack_bias(const float* __restrict__ qb,
                                                 const float* __restrict__ kb,
                                                 float* __restrict__ dst) {
  const int i = blockIdx.x * 256 + threadIdx.x;
  if (i < 512) dst[i] = qb[i];
  else if (i < 1024) dst[i] = kb[i - 512];
}

__global__ __launch_bounds__(256) void zero_f32(float* __restrict__ p) {
  ((f32x4*)p)[blockIdx.x * 256 + threadIdx.x] = f32x4{0.f, 0.f, 0.f, 0.f};
}

// ---------------------------------------------------------------------------
extern "C" void kernel_launch(void* const* d_in, const int* in_sizes, int n_in,
                              void* d_out, int out_size, void* d_ws, size_t ws_size,
                              hipStream_t stream) {
  const float* x     = (const float*)d_in[0];
  const float* gamma = (const float*)d_in[1];
  const float* beta  = (const float*)d_in[2];
  const float* q_w   = (const float*)d_in[3];
  const float* q_b   = (const float*)d_in[4];
  const float* k_w   = (const float*)d_in[5];
  const float* k_b   = (const float*)d_in[6];
  const float* p_w   = (const float*)d_in[7];
  const float* p_b   = (const float*)d_in[8];
  float* out = (float*)d_out;

  constexpr int B = 8, C = 512, N = 4096;
  constexpr size_t NC = (size_t)N * C;        // 2M elems per batch [n][c]
  constexpr size_t NN = (size_t)N * N;        // 16M elems per batch attn

  char* ws = (char*)d_ws;
  size_t off = 0;
  auto alloc = [&](size_t bytes) {
    void* p = ws + off;
    off += (bytes + 255) & ~(size_t)255;
    return p;
  };

  __hip_bfloat16* wqk = (__hip_bfloat16*)alloc((size_t)1024 * 512 * 2); // [wq;wk]
  __hip_bfloat16* wp  = (__hip_bfloat16*)alloc((size_t)C * C * 2);
  float* bias_qk      = (float*)alloc(1024 * 4);
  float2* stats       = (float2*)alloc((size_t)B * 32 * sizeof(float2));
  // R1: 64 MB region. Phase 1: rt[b][n][c] bf16 (32 MB). Phase 2: ot fp32
  // accumulator (64 MB, split-K) OR otb bf16 (32 MB, S==1).
  void* R1            = alloc(B * NC * 4);
  __hip_bfloat16* qkt = (__hip_bfloat16*)alloc(B * (size_t)N * 1024 * 2); // [b][n][q|k]
  __hip_bfloat16* kc  = (__hip_bfloat16*)alloc(B * NC * 2);               // [b][c][m]
  const size_t base_off = off;

  // attention score chunk: G batches at a time
  const size_t attn_b_bytes = NN * 2;
  size_t avail = (ws_size > base_off) ? ws_size - base_off : attn_b_bytes;
  int G = (int)(avail / attn_b_bytes);
  if (G < 1) G = 1;
  if (G > 8) G = 8;
  __hip_bfloat16* attn = (__hip_bfloat16*)alloc(attn_b_bytes * G);
  const int S = (G == 1) ? 8 : (G == 2) ? 4 : (G <= 5) ? 2 : 1;

  __hip_bfloat16* rt = (__hip_bfloat16*)R1;
  float* ot_f32      = (float*)R1;
  __hip_bfloat16* otb = (S > 1) ? attn /* free after chunk loop */
                                : (__hip_bfloat16*)R1;

  const dim3 blk(256);
  const float scale = 0.044194173824159216f;  // 512^-0.5 (applied in QK^T)

  cvt_bf16<<<dim3(256), blk, 0, stream>>>(q_w, wqk, C * C);
  cvt_bf16<<<dim3(256), blk, 0, stream>>>(k_w, wqk + (size_t)C * C, C * C);
  cvt_bf16<<<dim3(256), blk, 0, stream>>>(p_w, wp, C * C);
  pack_bias<<<dim3(4), blk, 0, stream>>>(q_b, k_b, bias_qk);

  gn_stats<<<dim3(B * 32), blk, 0, stream>>>(x, stats);
  gn_apply<<<dim3(64, B), blk, 0, stream>>>(x, stats, gamma, beta, rt);

  // merged q|k projection: qkt[b][n][m'] (m'<512: q+qb, m'>=512: k+kb)
  gemm_tn<1, false, true, false><<<dim3(32, 8, B), blk, 0, stream>>>(
      wqk, C, 0, rt, C, NC, qkt, 1024, (size_t)N * 1024,
      bias_qk, nullptr, 0, 1.f, C, 1);

  // kc[b][c][m] = k channel-major (for PV A-operand)
  gemm_tn<2, false, true, false><<<dim3(4, 32, B), blk, 0, stream>>>(
      rt, C, NC, wqk + (size_t)C * C, C, 0, kc, N, NC,
      k_b, nullptr, 0, 1.f, C, 1);

  if (S > 1)  // zero the fp32 PV accumulator (rt is dead after kc GEMM)
    zero_f32<<<dim3(16384), blk, 0, stream>>>(ot_f32);

  for (int b0 = 0; b0 < B; ) {
    const int Gc = (B - b0 < G) ? (B - b0) : G;
    // scores[n][m] = scale * sum_c k[m][c] * q[n][c]
    gemm_tn<0, false, true, false><<<dim3(32, 32, Gc), blk, 0, stream>>>(
        qkt + (size_t)b0 * N * 1024 + 512, 1024, (size_t)N * 1024,
        qkt + (size_t)b0 * N * 1024,       1024, (size_t)N * 1024,
        attn, N, NN, nullptr, nullptr, 0, scale, C, 1);

    softmax_rows<<<dim3(Gc * N), blk, 0, stream>>>(attn);

    // O[n][c] = sum_m kc[c][m] * attn[n][m]   (split-K over m)
    if (S > 1) {
      gemm_tn<0, false, false, true><<<dim3(32, 4, Gc * S), blk, 0, stream>>>(
          kc + (size_t)b0 * NC, N, NC, attn, N, NN,
          ot_f32 + (size_t)b0 * NC, C, NC,
          nullptr, nullptr, 0, 1.f, N / S, S);
    } else {
      gemm_tn<0, false, true, false><<<dim3(32, 4, Gc), blk, 0, stream>>>(
          kc + (size_t)b0 * NC, N, NC, attn, N, NN,
          otb + (size_t)b0 * NC, C, NC,
          nullptr, nullptr, 0, 1.f, N, 1);
    }
    b0 += Gc;
  }

  if (S > 1)  // compact fp32 accumulator -> bf16 (into attn region, now free)
    cvt_bf16<<<dim3(16384), blk, 0, stream>>>(ot_f32, otb, (int)(B * NC));

  // out[o][n] = Wp . O + pb + x
  gemm_tn<2, true, false, false><<<dim3(4, 32, B), blk, 0, stream>>>(
      otb, C, NC, wp, C, 0, out, N, NC, p_b, x, NC, 1.f, C, 1);
}

// Round 3
// 1597.211 us; speedup vs baseline: 1.0269x; 1.0269x over previous
//
#include <hip/hip_runtime.h>
#include <hip/hip_bf16.h>
#include <cstdint>

#define DEVI __device__ __forceinline__

typedef __attribute__((ext_vector_type(8))) short short8;
typedef __attribute__((ext_vector_type(4))) float f32x4;
typedef unsigned int u32;
typedef unsigned short u16;

DEVI u16 f2bf(float f) {
  __hip_bfloat16 h = __float2bfloat16(f);
  return *reinterpret_cast<u16*>(&h);
}
DEVI float bf2f_lo(u32 u) { return __uint_as_float(u << 16); }
DEVI float bf2f_hi(u32 u) { return __uint_as_float(u & 0xffff0000u); }

// async global->LDS, 16B per lane. LDS dest must be wave-uniform base + lane*16.
DEVI void async_cp16(const __hip_bfloat16* g, __hip_bfloat16* l) {
  __builtin_amdgcn_global_load_lds(
      (const __attribute__((address_space(1))) u32*)(uintptr_t)g,
      (__attribute__((address_space(3))) u32*)(uintptr_t)l, 16, 0, 0);
}

// ---------------------------------------------------------------------------
// Generic TN GEMM: Z[n'][m'] = alpha * (sum_k A[m'][k]*B[n'][k] + bias)
// A: M x K (K contiguous, lda), B: N x K (ldb). bf16. Tile 128x128, BK=32.
// Z addr = n'*ldz + m'. BIAS_MODE: 0 none, 1 per-M', 2 per-N'.
// Split-K: blockIdx.z = batch*nsplit + s; k-window = [s*K, (s+1)*K).
// ATOMIC: Z is fp32, accumulate with atomicAdd (caller pre-initializes Z).
// ---------------------------------------------------------------------------
template<int BIAS_MODE, bool OUT_BF16, bool ATOMIC>
__global__ __launch_bounds__(256) void gemm_tn(
    const __hip_bfloat16* __restrict__ A, int lda, size_t sA,
    const __hip_bfloat16* __restrict__ B, int ldb, size_t sB,
    void* __restrict__ Zv, int ldz, size_t sZ,
    const float* __restrict__ bias,
    float alpha, int K, int nsplit)
{
  __shared__ __hip_bfloat16 lsA[128 * 32];
  __shared__ __hip_bfloat16 lsB[128 * 32];
  const int t    = threadIdx.x;
  const int bz   = blockIdx.z;
  const int bb   = bz / nsplit;          // batch index
  const int sp   = bz - bb * nsplit;     // split index
  const size_t koff = (size_t)sp * K;
  const int n0   = blockIdx.x * 128;
  const int m0   = blockIdx.y * 128;
  const __hip_bfloat16* Ab = A + (size_t)bb * sA + koff;
  const __hip_bfloat16* Bb = B + (size_t)bb * sB + koff;

  const int lane = t & 63;
  const int quad = lane >> 4;
  const int l16  = lane & 15;
  const int wave = t >> 6;
  const int wm   = (wave >> 1) * 64;
  const int wn   = (wave & 1) * 64;

  const int rowc = t >> 2;
  const int kc   = (t & 3) * 8;
  const __hip_bfloat16* ga0 = Ab + (size_t)(m0 + rowc) * lda + kc;
  const __hip_bfloat16* ga1 = Ab + (size_t)(m0 + rowc + 64) * lda + kc;
  const __hip_bfloat16* gb0 = Bb + (size_t)(n0 + rowc) * ldb + kc;
  const __hip_bfloat16* gb1 = Bb + (size_t)(n0 + rowc + 64) * ldb + kc;
  __hip_bfloat16* la0 = lsA + t * 8;
  __hip_bfloat16* la1 = lsA + 2048 + t * 8;
  __hip_bfloat16* lb0 = lsB + t * 8;
  __hip_bfloat16* lb1 = lsB + 2048 + t * 8;

  f32x4 acc[4][4] = {};

  for (int k0 = 0; k0 < K; k0 += 32) {
    __syncthreads();
    async_cp16(ga0, la0);
    async_cp16(ga1, la1);
    async_cp16(gb0, lb0);
    async_cp16(gb1, lb1);
    ga0 += 32; ga1 += 32; gb0 += 32; gb1 += 32;
    __syncthreads();

    short8 af[4], bf[4];
#pragma unroll
    for (int i = 0; i < 4; ++i)
      af[i] = *(const short8*)(lsA + (wm + i * 16 + l16) * 32 + quad * 8);
#pragma unroll
    for (int j = 0; j < 4; ++j)
      bf[j] = *(const short8*)(lsB + (wn + j * 16 + l16) * 32 + quad * 8);
#pragma unroll
    for (int i = 0; i < 4; ++i)
#pragma unroll
      for (int j = 0; j < 4; ++j)
        acc[i][j] = __builtin_amdgcn_mfma_f32_16x16x32_bf16(af[i], bf[j], acc[i][j], 0, 0, 0);
  }

#pragma unroll
  for (int i = 0; i < 4; ++i) {
#pragma unroll
    for (int j = 0; j < 4; ++j) {
      const int m = m0 + wm + i * 16 + quad * 4;
      const int n = n0 + wn + j * 16 + l16;
      f32x4 v = acc[i][j];
      if (BIAS_MODE == 1) v += *(const f32x4*)(bias + m);
      else if (BIAS_MODE == 2) v += bias[n];
      v *= alpha;
      const size_t zoff = (size_t)n * ldz + m;
      if (ATOMIC) {
        float* zp = (float*)Zv + (size_t)bb * sZ + zoff;
        atomicAdd(zp + 0, v[0]);
        atomicAdd(zp + 1, v[1]);
        atomicAdd(zp + 2, v[2]);
        atomicAdd(zp + 3, v[3]);
      } else if (OUT_BF16) {
        union { u16 s[4]; uint2 q; } pk;
        pk.s[0] = f2bf(v[0]); pk.s[1] = f2bf(v[1]);
        pk.s[2] = f2bf(v[2]); pk.s[3] = f2bf(v[3]);
        *(uint2*)((__hip_bfloat16*)Zv + (size_t)bb * sZ + zoff) = pk.q;
      } else {
        *(f32x4*)((float*)Zv + (size_t)bb * sZ + zoff) = v;
      }
    }
  }
}

// ---------------------------------------------------------------------------
__global__ __launch_bounds__(256) void gn_stats(const float* __restrict__ x,
                                                float2* __restrict__ stats) {
  const int bg = blockIdx.x;
  const f32x4* p = (const f32x4*)(x + (size_t)bg * 65536);
  float s = 0.f, s2 = 0.f;
  for (int i = threadIdx.x; i < 16384; i += 256) {
    f32x4 v = p[i];
    s  += v[0] + v[1] + v[2] + v[3];
    s2 += v[0]*v[0] + v[1]*v[1] + v[2]*v[2] + v[3]*v[3];
  }
  for (int o = 32; o > 0; o >>= 1) { s += __shfl_down(s, o); s2 += __shfl_down(s2, o); }
  __shared__ float ws[4], ws2[4];
  const int wave = threadIdx.x >> 6;
  if ((threadIdx.x & 63) == 0) { ws[wave] = s; ws2[wave] = s2; }
  __syncthreads();
  if (threadIdx.x == 0) {
    float S  = ws[0] + ws[1] + ws[2] + ws[3];
    float S2 = ws2[0] + ws2[1] + ws2[2] + ws2[3];
    float mu = S * (1.f / 65536.f);
    float var = S2 * (1.f / 65536.f) - mu * mu;
    stats[bg] = make_float2(mu, rsqrtf(var + 1e-6f));
  }
}

// GroupNorm apply + transpose: x[b][c][n] fp32 -> r_t[b][n][c] bf16.
__global__ __launch_bounds__(256) void gn_apply(const float* __restrict__ x,
                                                const float2* __restrict__ stats,
                                                const float* __restrict__ gamma,
                                                const float* __restrict__ beta,
                                                __hip_bfloat16* __restrict__ rt) {
  const int b = blockIdx.y, n0 = blockIdx.x * 64;
  __shared__ float tile[64][65];
  const int t  = threadIdx.x;
  const int cl = t >> 2;
  const int q4 = (t & 3) * 4;
  for (int cc = 0; cc < 8; ++cc) {
    const int c = cc * 64 + cl;
    const float2 ms = stats[b * 32 + (c >> 4)];
    const float ga = gamma[c] * ms.y;
    const float be = beta[c] - ms.x * ga;
    const float* src = x + ((size_t)b * 512 + c) * 4096 + n0;
#pragma unroll
    for (int p = 0; p < 4; ++p) {
      f32x4 v = *(const f32x4*)(src + q4 + p * 16);
      tile[cl][q4 + p * 16 + 0] = fmaf(v[0], ga, be);
      tile[cl][q4 + p * 16 + 1] = fmaf(v[1], ga, be);
      tile[cl][q4 + p * 16 + 2] = fmaf(v[2], ga, be);
      tile[cl][q4 + p * 16 + 3] = fmaf(v[3], ga, be);
    }
    __syncthreads();
    const int nw = t >> 2;
    const int cw = (t & 3) * 16;
    union { u16 s[16]; uint4 q[2]; } pk;
#pragma unroll
    for (int j = 0; j < 16; ++j) pk.s[j] = f2bf(tile[cw + j][nw]);
    __hip_bfloat16* dst = rt + ((size_t)b * 4096 + n0 + nw) * 512 + cc * 64 + cw;
    *(uint4*)dst = pk.q[0];
    *((uint4*)dst + 1) = pk.q[1];
    __syncthreads();
  }
}

// Row softmax, in place, bf16 storage / fp32 math. One block per 4096-row.
__global__ __launch_bounds__(256) void softmax_rows(__hip_bfloat16* __restrict__ a) {
  __hip_bfloat16* p = a + (size_t)blockIdx.x * 4096;
  const int t = threadIdx.x;
  uint4 r0 = *(uint4*)(p + t * 16);
  uint4 r1 = *(uint4*)(p + t * 16 + 8);
  float v[16];
  v[0]=bf2f_lo(r0.x); v[1]=bf2f_hi(r0.x); v[2]=bf2f_lo(r0.y); v[3]=bf2f_hi(r0.y);
  v[4]=bf2f_lo(r0.z); v[5]=bf2f_hi(r0.z); v[6]=bf2f_lo(r0.w); v[7]=bf2f_hi(r0.w);
  v[8]=bf2f_lo(r1.x); v[9]=bf2f_hi(r1.x); v[10]=bf2f_lo(r1.y); v[11]=bf2f_hi(r1.y);
  v[12]=bf2f_lo(r1.z); v[13]=bf2f_hi(r1.z); v[14]=bf2f_lo(r1.w); v[15]=bf2f_hi(r1.w);

  __shared__ float red[4];
  const int wave = t >> 6, lane = t & 63;

  float mx = v[0];
#pragma unroll
  for (int i = 1; i < 16; ++i) mx = fmaxf(mx, v[i]);
  for (int o = 32; o > 0; o >>= 1) mx = fmaxf(mx, __shfl_down(mx, o));
  if (lane == 0) red[wave] = mx;
  __syncthreads();
  mx = fmaxf(fmaxf(red[0], red[1]), fmaxf(red[2], red[3]));
  __syncthreads();

  float sum = 0.f;
#pragma unroll
  for (int i = 0; i < 16; ++i) { v[i] = __expf(v[i] - mx); sum += v[i]; }
  for (int o = 32; o > 0; o >>= 1) sum += __shfl_down(sum, o);
  if (lane == 0) red[wave] = sum;
  __syncthreads();
  sum = red[0] + red[1] + red[2] + red[3];
  const float inv = 1.f / sum;

  union { u16 s[16]; uint4 q[2]; } pk;
#pragma unroll
  for (int i = 0; i < 16; ++i) pk.s[i] = f2bf(v[i] * inv);
  *(uint4*)(p + t * 16) = pk.q[0];
  *(uint4*)(p + t * 16 + 8) = pk.q[1];
}

__global__ __launch_bounds__(256) void cvt_bf16(const float* __restrict__ s,
                                                __hip_bfloat16* __restrict__ d, int n) {
  const int i = (blockIdx.x * 256 + threadIdx.x) * 4;
  if (i < n) {
    f32x4 v = *(const f32x4*)(s + i);
    union { u16 s4[4]; uint2 q; } pk;
    pk.s4[0] = f2bf(v[0]); pk.s4[1] = f2bf(v[1]);
    pk.s4[2] = f2bf(v[2]); pk.s4[3] = f2bf(v[3]);
    *(uint2*)(d + i) = pk.q;
  }
}

__global__ __launch_bounds__(256) void pack_bias(const float* __restrict__ qb,
                                                 const float* __restrict__ kb,
                                                 float* __restrict__ dst) {
  const int i = blockIdx.x * 256 + threadIdx.x;
  if (i < 512) dst[i] = qb[i];
  else if (i < 1024) dst[i] = kb[i - 512];
}

// out[b][c][n] = x[b][c][n] + pb[c]   (pre-init for atomic PV-proj GEMM)
__global__ __launch_bounds__(256) void out_init(const float* __restrict__ x,
                                                const float* __restrict__ pb,
                                                float* __restrict__ out) {
  const size_t i = ((size_t)blockIdx.x * 256 + threadIdx.x) * 4;
  const int c = (int)((i >> 12) & 511);  // (i / 4096) % 512
  f32x4 v = *(const f32x4*)(x + i);
  const float b = pb[c];
  v[0] += b; v[1] += b; v[2] += b; v[3] += b;
  *(f32x4*)(out + i) = v;
}

// ---------------------------------------------------------------------------
extern "C" void kernel_launch(void* const* d_in, const int* in_sizes, int n_in,
                              void* d_out, int out_size, void* d_ws, size_t ws_size,
                              hipStream_t stream) {
  const float* x     = (const float*)d_in[0];
  const float* gamma = (const float*)d_in[1];
  const float* beta  = (const float*)d_in[2];
  const float* q_w   = (const float*)d_in[3];
  const float* q_b   = (const float*)d_in[4];
  const float* k_w   = (const float*)d_in[5];
  const float* k_b   = (const float*)d_in[6];
  const float* p_w   = (const float*)d_in[7];
  const float* p_b   = (const float*)d_in[8];
  float* out = (float*)d_out;

  constexpr int B = 8, C = 512, N = 4096;
  constexpr size_t NC = (size_t)N * C;        // 2M elems per batch
  constexpr size_t NN = (size_t)N * N;        // 16M elems per batch attn

  char* ws = (char*)d_ws;
  size_t off = 0;
  auto alloc = [&](size_t bytes) {
    void* p = ws + off;
    off += (bytes + 255) & ~(size_t)255;
    return p;
  };

  __hip_bfloat16* wqk = (__hip_bfloat16*)alloc((size_t)1024 * 512 * 2); // [wq;wk]
  __hip_bfloat16* wp  = (__hip_bfloat16*)alloc((size_t)C * C * 2);
  float* bias_qk      = (float*)alloc(1024 * 4);
  float2* stats       = (float2*)alloc((size_t)B * 32 * sizeof(float2));
  __hip_bfloat16* rt  = (__hip_bfloat16*)alloc(B * NC * 2);               // [b][n][c]
  __hip_bfloat16* qkt = (__hip_bfloat16*)alloc(B * (size_t)N * 1024 * 2); // [b][n][q|k]
  __hip_bfloat16* wpv = (__hip_bfloat16*)alloc(B * NC * 2);               // [b][o][m]
  const size_t base_off = off;

  // attention chunk: G batches at a time. G=2 keeps the chunk working set
  // (attn 64 MB + wpv 64 MB + out 64 MB) inside the 256 MB L3.
  const size_t attn_b_bytes = NN * 2;
  size_t avail = (ws_size > base_off) ? ws_size - base_off : 0;
  int G = (int)(avail / attn_b_bytes);
  if (G < 1) G = 1;
  if (G > 2) G = 2;
  __hip_bfloat16* attn = (__hip_bfloat16*)alloc(attn_b_bytes * G);
  const int S = (G == 1) ? 8 : 4;   // split-K factor for PV-proj

  const dim3 blk(256);
  const float scale = 0.044194173824159216f;  // 512^-0.5 (alpha of QK^T)

  cvt_bf16<<<dim3(256), blk, 0, stream>>>(q_w, wqk, C * C);
  cvt_bf16<<<dim3(256), blk, 0, stream>>>(k_w, wqk + (size_t)C * C, C * C);
  cvt_bf16<<<dim3(256), blk, 0, stream>>>(p_w, wp, C * C);
  pack_bias<<<dim3(4), blk, 0, stream>>>(q_b, k_b, bias_qk);

  gn_stats<<<dim3(B * 32), blk, 0, stream>>>(x, stats);
  gn_apply<<<dim3(64, B), blk, 0, stream>>>(x, stats, gamma, beta, rt);

  // merged q|k projection: qkt[b][n][m'] (m'<512: q+qb, m'>=512: k+kb)
  gemm_tn<1, true, false><<<dim3(32, 8, B), blk, 0, stream>>>(
      wqk, C, 0, rt, C, NC, qkt, 1024, (size_t)N * 1024,
      bias_qk, 1.f, C, 1);

  // wpv[b][o][m] = sum_c wp[o][c] * k_hat[m][c]   (V = k_hat, bias included)
  // Z[n'=o][m'=m]: A = k-half of qkt (M'=m), B = wp (N'=o).
  gemm_tn<0, true, false><<<dim3(4, 32, B), blk, 0, stream>>>(
      qkt + 512, 1024, (size_t)N * 1024, wp, C, 0,
      wpv, N, NC, nullptr, 1.f, C, 1);

  // out = x + proj bias (atomic GEMM accumulates on top)
  out_init<<<dim3(16384), blk, 0, stream>>>(x, p_b, out);

  for (int b0 = 0; b0 < B; ) {
    const int Gc = (B - b0 < G) ? (B - b0) : G;
    // scores[n][m] = scale * sum_c k_hat[m][c] * q_hat[n][c]
    gemm_tn<0, true, false><<<dim3(32, 32, Gc), blk, 0, stream>>>(
        qkt + (size_t)b0 * N * 1024 + 512, 1024, (size_t)N * 1024,
        qkt + (size_t)b0 * N * 1024,       1024, (size_t)N * 1024,
        attn, N, NN, nullptr, scale, C, 1);

    softmax_rows<<<dim3(Gc * N), blk, 0, stream>>>(attn);

    // out[o][n] += sum_m wpv[o][m] * attn[n][m]   (split-K over m, atomics)
    // Z[n'=o][m'=n]: A = attn (M'=n, lda=N), B = wpv (N'=o, ldb=N).
    gemm_tn<0, false, true><<<dim3(4, 32, Gc * S), blk, 0, stream>>>(
        attn, N, NN, wpv + (size_t)b0 * NC, N, NC,
        out + (size_t)b0 * NC, N, NC,
        nullptr, 1.f, N / S, S);
    b0 += Gc;
  }
}

// Round 4
// 1160.088 us; speedup vs baseline: 1.4139x; 1.3768x over previous
//
#include <hip/hip_runtime.h>
#include <hip/hip_bf16.h>
#include <cstdint>

#define DEVI __device__ __forceinline__

typedef __attribute__((ext_vector_type(8))) short short8;
typedef __attribute__((ext_vector_type(4))) float f32x4;
typedef unsigned int u32;
typedef unsigned short u16;

DEVI u16 f2bf(float f) {
  __hip_bfloat16 h = __float2bfloat16(f);
  return *reinterpret_cast<u16*>(&h);
}
DEVI float bf2f_lo(u32 u) { return __uint_as_float(u << 16); }
DEVI float bf2f_hi(u32 u) { return __uint_as_float(u & 0xffff0000u); }

// async global->LDS, 16B per lane. LDS dest must be wave-uniform base + lane*16.
DEVI void async_cp16(const __hip_bfloat16* g, __hip_bfloat16* l) {
  __builtin_amdgcn_global_load_lds(
      (const __attribute__((address_space(1))) u32*)(uintptr_t)g,
      (__attribute__((address_space(3))) u32*)(uintptr_t)l, 16, 0, 0);
}

// ---------------------------------------------------------------------------
// Generic TN GEMM: Z[n'][m'] = alpha * (sum_k A[m'][k]*B[n'][k] + bias)
// A: M x K (K contiguous, lda), B: N x K (ldb). bf16. Tile 128x128, BK=32.
// Z addr = n'*ldz + m'. BIAS_MODE: 0 none, 1 per-M', 2 per-N'.
// Split-K: blockIdx.z = batch*nsplit + s; k-window = [s*K, (s+1)*K).
// SPLITOUT: Z is fp32 partial, indexed by bz (each (batch,split) private slice;
//           plain stores, NO atomics — reducer sums the slices).
// ---------------------------------------------------------------------------
template<int BIAS_MODE, bool OUT_BF16, bool SPLITOUT>
__global__ __launch_bounds__(256) void gemm_tn(
    const __hip_bfloat16* __restrict__ A, int lda, size_t sA,
    const __hip_bfloat16* __restrict__ B, int ldb, size_t sB,
    void* __restrict__ Zv, int ldz, size_t sZ,
    const float* __restrict__ bias,
    float alpha, int K, int nsplit)
{
  __shared__ __hip_bfloat16 lsA[128 * 32];
  __shared__ __hip_bfloat16 lsB[128 * 32];
  const int t    = threadIdx.x;
  const int bz   = blockIdx.z;
  const int bb   = bz / nsplit;          // batch index
  const int sp   = bz - bb * nsplit;     // split index
  const size_t koff = (size_t)sp * K;
  const int n0   = blockIdx.x * 128;
  const int m0   = blockIdx.y * 128;
  const __hip_bfloat16* Ab = A + (size_t)bb * sA + koff;
  const __hip_bfloat16* Bb = B + (size_t)bb * sB + koff;

  const int lane = t & 63;
  const int quad = lane >> 4;
  const int l16  = lane & 15;
  const int wave = t >> 6;
  const int wm   = (wave >> 1) * 64;
  const int wn   = (wave & 1) * 64;

  const int rowc = t >> 2;
  const int kc   = (t & 3) * 8;
  const __hip_bfloat16* ga0 = Ab + (size_t)(m0 + rowc) * lda + kc;
  const __hip_bfloat16* ga1 = Ab + (size_t)(m0 + rowc + 64) * lda + kc;
  const __hip_bfloat16* gb0 = Bb + (size_t)(n0 + rowc) * ldb + kc;
  const __hip_bfloat16* gb1 = Bb + (size_t)(n0 + rowc + 64) * ldb + kc;
  __hip_bfloat16* la0 = lsA + t * 8;
  __hip_bfloat16* la1 = lsA + 2048 + t * 8;
  __hip_bfloat16* lb0 = lsB + t * 8;
  __hip_bfloat16* lb1 = lsB + 2048 + t * 8;

  f32x4 acc[4][4] = {};

  for (int k0 = 0; k0 < K; k0 += 32) {
    __syncthreads();
    async_cp16(ga0, la0);
    async_cp16(ga1, la1);
    async_cp16(gb0, lb0);
    async_cp16(gb1, lb1);
    ga0 += 32; ga1 += 32; gb0 += 32; gb1 += 32;
    __syncthreads();

    short8 af[4], bf[4];
#pragma unroll
    for (int i = 0; i < 4; ++i)
      af[i] = *(const short8*)(lsA + (wm + i * 16 + l16) * 32 + quad * 8);
#pragma unroll
    for (int j = 0; j < 4; ++j)
      bf[j] = *(const short8*)(lsB + (wn + j * 16 + l16) * 32 + quad * 8);
#pragma unroll
    for (int i = 0; i < 4; ++i)
#pragma unroll
      for (int j = 0; j < 4; ++j)
        acc[i][j] = __builtin_amdgcn_mfma_f32_16x16x32_bf16(af[i], bf[j], acc[i][j], 0, 0, 0);
  }

#pragma unroll
  for (int i = 0; i < 4; ++i) {
#pragma unroll
    for (int j = 0; j < 4; ++j) {
      const int m = m0 + wm + i * 16 + quad * 4;
      const int n = n0 + wn + j * 16 + l16;
      f32x4 v = acc[i][j];
      if (BIAS_MODE == 1) v += *(const f32x4*)(bias + m);
      else if (BIAS_MODE == 2) v += bias[n];
      v *= alpha;
      const size_t zoff = (size_t)n * ldz + m;
      if (SPLITOUT) {
        *(f32x4*)((float*)Zv + (size_t)bz * sZ + zoff) = v;
      } else if (OUT_BF16) {
        union { u16 s[4]; uint2 q; } pk;
        pk.s[0] = f2bf(v[0]); pk.s[1] = f2bf(v[1]);
        pk.s[2] = f2bf(v[2]); pk.s[3] = f2bf(v[3]);
        *(uint2*)((__hip_bfloat16*)Zv + (size_t)bb * sZ + zoff) = pk.q;
      } else {
        *(f32x4*)((float*)Zv + (size_t)bb * sZ + zoff) = v;
      }
    }
  }
}

// ---------------------------------------------------------------------------
__global__ __launch_bounds__(256) void gn_stats(const float* __restrict__ x,
                                                float2* __restrict__ stats) {
  const int bg = blockIdx.x;
  const f32x4* p = (const f32x4*)(x + (size_t)bg * 65536);
  float s = 0.f, s2 = 0.f;
  for (int i = threadIdx.x; i < 16384; i += 256) {
    f32x4 v = p[i];
    s  += v[0] + v[1] + v[2] + v[3];
    s2 += v[0]*v[0] + v[1]*v[1] + v[2]*v[2] + v[3]*v[3];
  }
  for (int o = 32; o > 0; o >>= 1) { s += __shfl_down(s, o); s2 += __shfl_down(s2, o); }
  __shared__ float ws[4], ws2[4];
  const int wave = threadIdx.x >> 6;
  if ((threadIdx.x & 63) == 0) { ws[wave] = s; ws2[wave] = s2; }
  __syncthreads();
  if (threadIdx.x == 0) {
    float S  = ws[0] + ws[1] + ws[2] + ws[3];
    float S2 = ws2[0] + ws2[1] + ws2[2] + ws2[3];
    float mu = S * (1.f / 65536.f);
    float var = S2 * (1.f / 65536.f) - mu * mu;
    stats[bg] = make_float2(mu, rsqrtf(var + 1e-6f));
  }
}

// GroupNorm apply + transpose: x[b][c][n] fp32 -> r_t[b][n][c] bf16.
__global__ __launch_bounds__(256) void gn_apply(const float* __restrict__ x,
                                                const float2* __restrict__ stats,
                                                const float* __restrict__ gamma,
                                                const float* __restrict__ beta,
                                                __hip_bfloat16* __restrict__ rt) {
  const int b = blockIdx.y, n0 = blockIdx.x * 64;
  __shared__ float tile[64][65];
  const int t  = threadIdx.x;
  const int cl = t >> 2;
  const int q4 = (t & 3) * 4;
  for (int cc = 0; cc < 8; ++cc) {
    const int c = cc * 64 + cl;
    const float2 ms = stats[b * 32 + (c >> 4)];
    const float ga = gamma[c] * ms.y;
    const float be = beta[c] - ms.x * ga;
    const float* src = x + ((size_t)b * 512 + c) * 4096 + n0;
#pragma unroll
    for (int p = 0; p < 4; ++p) {
      f32x4 v = *(const f32x4*)(src + q4 + p * 16);
      tile[cl][q4 + p * 16 + 0] = fmaf(v[0], ga, be);
      tile[cl][q4 + p * 16 + 1] = fmaf(v[1], ga, be);
      tile[cl][q4 + p * 16 + 2] = fmaf(v[2], ga, be);
      tile[cl][q4 + p * 16 + 3] = fmaf(v[3], ga, be);
    }
    __syncthreads();
    const int nw = t >> 2;
    const int cw = (t & 3) * 16;
    union { u16 s[16]; uint4 q[2]; } pk;
#pragma unroll
    for (int j = 0; j < 16; ++j) pk.s[j] = f2bf(tile[cw + j][nw]);
    __hip_bfloat16* dst = rt + ((size_t)b * 4096 + n0 + nw) * 512 + cc * 64 + cw;
    *(uint4*)dst = pk.q[0];
    *((uint4*)dst + 1) = pk.q[1];
    __syncthreads();
  }
}

// Row softmax, in place, bf16 storage / fp32 math. One block per 4096-row.
__global__ __launch_bounds__(256) void softmax_rows(__hip_bfloat16* __restrict__ a) {
  __hip_bfloat16* p = a + (size_t)blockIdx.x * 4096;
  const int t = threadIdx.x;
  uint4 r0 = *(uint4*)(p + t * 16);
  uint4 r1 = *(uint4*)(p + t * 16 + 8);
  float v[16];
  v[0]=bf2f_lo(r0.x); v[1]=bf2f_hi(r0.x); v[2]=bf2f_lo(r0.y); v[3]=bf2f_hi(r0.y);
  v[4]=bf2f_lo(r0.z); v[5]=bf2f_hi(r0.z); v[6]=bf2f_lo(r0.w); v[7]=bf2f_hi(r0.w);
  v[8]=bf2f_lo(r1.x); v[9]=bf2f_hi(r1.x); v[10]=bf2f_lo(r1.y); v[11]=bf2f_hi(r1.y);
  v[12]=bf2f_lo(r1.z); v[13]=bf2f_hi(r1.z); v[14]=bf2f_lo(r1.w); v[15]=bf2f_hi(r1.w);

  __shared__ float red[4];
  const int wave = t >> 6, lane = t & 63;

  float mx = v[0];
#pragma unroll
  for (int i = 1; i < 16; ++i) mx = fmaxf(mx, v[i]);
  for (int o = 32; o > 0; o >>= 1) mx = fmaxf(mx, __shfl_down(mx, o));
  if (lane == 0) red[wave] = mx;
  __syncthreads();
  mx = fmaxf(fmaxf(red[0], red[1]), fmaxf(red[2], red[3]));
  __syncthreads();

  float sum = 0.f;
#pragma unroll
  for (int i = 0; i < 16; ++i) { v[i] = __expf(v[i] - mx); sum += v[i]; }
  for (int o = 32; o > 0; o >>= 1) sum += __shfl_down(sum, o);
  if (lane == 0) red[wave] = sum;
  __syncthreads();
  sum = red[0] + red[1] + red[2] + red[3];
  const float inv = 1.f / sum;

  union { u16 s[16]; uint4 q[2]; } pk;
#pragma unroll
  for (int i = 0; i < 16; ++i) pk.s[i] = f2bf(v[i] * inv);
  *(uint4*)(p + t * 16) = pk.q[0];
  *(uint4*)(p + t * 16 + 8) = pk.q[1];
}

__global__ __launch_bounds__(256) void cvt_bf16(const float* __restrict__ s,
                                                __hip_bfloat16* __restrict__ d, int n) {
  const int i = (blockIdx.x * 256 + threadIdx.x) * 4;
  if (i < n) {
    f32x4 v = *(const f32x4*)(s + i);
    union { u16 s4[4]; uint2 q; } pk;
    pk.s4[0] = f2bf(v[0]); pk.s4[1] = f2bf(v[1]);
    pk.s4[2] = f2bf(v[2]); pk.s4[3] = f2bf(v[3]);
    *(uint2*)(d + i) = pk.q;
  }
}

__global__ __launch_bounds__(256) void pack_bias(const float* __restrict__ qb,
                                                 const float* __restrict__ kb,
                                                 float* __restrict__ dst) {
  const int i = blockIdx.x * 256 + threadIdx.x;
  if (i < 512) dst[i] = qb[i];
  else if (i < 1024) dst[i] = kb[i - 512];
}

// out[b0+g][c][n] = x[...] + pb[c] + sum_s part[(g*S+s)][c][n]
// part slices are [g][s][C*N] fp32; grid (2048, Gc), 4 floats/thread.
__global__ __launch_bounds__(256) void reduce_out(
    const float* __restrict__ part, const float* __restrict__ x,
    const float* __restrict__ pb, float* __restrict__ out,
    int S, int b0) {
  constexpr size_t NC = (size_t)4096 * 512;
  const int g = blockIdx.y;
  const size_t r = ((size_t)blockIdx.x * 256 + threadIdx.x) * 4;
  const int c = (int)(r >> 12);          // r / 4096
  const float* ps = part + (size_t)g * S * NC + r;
  f32x4 v = *(const f32x4*)(x + (size_t)(b0 + g) * NC + r);
  const float b = pb[c];
  v[0] += b; v[1] += b; v[2] += b; v[3] += b;
  for (int s = 0; s < S; ++s) v += *(const f32x4*)(ps + (size_t)s * NC);
  *(f32x4*)(out + (size_t)(b0 + g) * NC + r) = v;
}

// ---------------------------------------------------------------------------
extern "C" void kernel_launch(void* const* d_in, const int* in_sizes, int n_in,
                              void* d_out, int out_size, void* d_ws, size_t ws_size,
                              hipStream_t stream) {
  const float* x     = (const float*)d_in[0];
  const float* gamma = (const float*)d_in[1];
  const float* beta  = (const float*)d_in[2];
  const float* q_w   = (const float*)d_in[3];
  const float* q_b   = (const float*)d_in[4];
  const float* k_w   = (const float*)d_in[5];
  const float* k_b   = (const float*)d_in[6];
  const float* p_w   = (const float*)d_in[7];
  const float* p_b   = (const float*)d_in[8];
  float* out = (float*)d_out;

  constexpr int B = 8, C = 512, N = 4096;
  constexpr size_t NC = (size_t)N * C;        // 2M elems per batch
  constexpr size_t NN = (size_t)N * N;        // 16M elems per batch attn

  char* ws = (char*)d_ws;
  size_t off = 0;
  auto alloc = [&](size_t bytes) {
    void* p = ws + off;
    off += (bytes + 255) & ~(size_t)255;
    return p;
  };

  __hip_bfloat16* wqk = (__hip_bfloat16*)alloc((size_t)1024 * 512 * 2); // [wq;wk]
  __hip_bfloat16* wp  = (__hip_bfloat16*)alloc((size_t)C * C * 2);
  float* bias_qk      = (float*)alloc(1024 * 4);
  float2* stats       = (float2*)alloc((size_t)B * 32 * sizeof(float2));
  __hip_bfloat16* rt  = (__hip_bfloat16*)alloc(B * NC * 2);               // [b][n][c]
  __hip_bfloat16* qkt = (__hip_bfloat16*)alloc(B * (size_t)N * 1024 * 2); // [b][n][q|k]
  __hip_bfloat16* wpv = (__hip_bfloat16*)alloc(B * NC * 2);               // [b][o][m]
  float* part         = (float*)alloc((size_t)8 * NC * 4);                // 67 MB
  const size_t base_off = off;

  // chunking: G batches per iteration, split-K factor S with G*S == 8
  // (part buffer holds G*S slices of NC fp32). G=2 keeps the chunk working
  // set (attn 67 MB + part 67 MB + slices) inside the 256 MB L3.
  const size_t attn_b_bytes = NN * 2;
  size_t avail = (ws_size > base_off) ? ws_size - base_off : 0;
  int G = 2, S = 4;
  if (avail < 2 * attn_b_bytes) { G = 1; S = 8; }
  if (avail < attn_b_bytes) { G = 1; S = 8; }  // last resort; assume it fits
  __hip_bfloat16* attn = (__hip_bfloat16*)alloc(attn_b_bytes * G);

  const dim3 blk(256);
  const float scale = 0.044194173824159216f;  // 512^-0.5 (alpha of QK^T)

  cvt_bf16<<<dim3(256), blk, 0, stream>>>(q_w, wqk, C * C);
  cvt_bf16<<<dim3(256), blk, 0, stream>>>(k_w, wqk + (size_t)C * C, C * C);
  cvt_bf16<<<dim3(256), blk, 0, stream>>>(p_w, wp, C * C);
  pack_bias<<<dim3(4), blk, 0, stream>>>(q_b, k_b, bias_qk);

  gn_stats<<<dim3(B * 32), blk, 0, stream>>>(x, stats);
  gn_apply<<<dim3(64, B), blk, 0, stream>>>(x, stats, gamma, beta, rt);

  // merged q|k projection: qkt[b][n][m'] (m'<512: q+qb, m'>=512: k+kb)
  gemm_tn<1, true, false><<<dim3(32, 8, B), blk, 0, stream>>>(
      wqk, C, 0, rt, C, NC, qkt, 1024, (size_t)N * 1024,
      bias_qk, 1.f, C, 1);

  // wpv[b][o][m] = sum_c wp[o][c] * k_hat[m][c]   (V = k_hat, bias included)
  gemm_tn<0, true, false><<<dim3(4, 32, B), blk, 0, stream>>>(
      qkt + 512, 1024, (size_t)N * 1024, wp, C, 0,
      wpv, N, NC, nullptr, 1.f, C, 1);

  for (int b0 = 0; b0 < B; ) {
    const int Gc = (B - b0 < G) ? (B - b0) : G;
    // scores[n][m] = scale * sum_c k_hat[m][c] * q_hat[n][c]
    gemm_tn<0, true, false><<<dim3(32, 32, Gc), blk, 0, stream>>>(
        qkt + (size_t)b0 * N * 1024 + 512, 1024, (size_t)N * 1024,
        qkt + (size_t)b0 * N * 1024,       1024, (size_t)N * 1024,
        attn, N, NN, nullptr, scale, C, 1);

    softmax_rows<<<dim3(Gc * N), blk, 0, stream>>>(attn);

    // part[g][s][o][n] = sum_{m in split s} wpv[o][m] * attn[n][m]
    // Z[n'=o][m'=n]: A = attn (M'=n, lda=N), B = wpv (N'=o, ldb=N).
    gemm_tn<0, false, true><<<dim3(4, 32, Gc * S), blk, 0, stream>>>(
        attn, N, NN, wpv + (size_t)b0 * NC, N, NC,
        part, N, NC, nullptr, 1.f, N / S, S);

    // out = x + pb + sum_s part
    reduce_out<<<dim3(2048, Gc), blk, 0, stream>>>(part, x, p_b, out, S, b0);
    b0 += Gc;
  }
}

// Round 5
// 1092.863 us; speedup vs baseline: 1.5008x; 1.0615x over previous
//
#include <hip/hip_runtime.h>
#include <hip/hip_bf16.h>
#include <cstdint>

#define DEVI __device__ __forceinline__

typedef __attribute__((ext_vector_type(8))) short short8;
typedef __attribute__((ext_vector_type(4))) float f32x4;
typedef unsigned int u32;
typedef unsigned short u16;

DEVI u16 f2bf(float f) {
  __hip_bfloat16 h = __float2bfloat16(f);
  return *reinterpret_cast<u16*>(&h);
}

// async global->LDS, 16B per lane. LDS dest must be wave-uniform base + lane*16.
DEVI void async_cp16(const __hip_bfloat16* g, __hip_bfloat16* l) {
  __builtin_amdgcn_global_load_lds(
      (const __attribute__((address_space(1))) u32*)(uintptr_t)g,
      (__attribute__((address_space(3))) u32*)(uintptr_t)l, 16, 0, 0);
}

// ---------------------------------------------------------------------------
// Generic TN GEMM: Z[n'][m'] = alpha * (sum_k A[m'][k]*B[n'][k] + bias)
// A: M x K (K contiguous, lda), B: N x K (ldb). bf16. Tile 128x128, BK=32.
// Z addr = n'*ldz + m'. BIAS_MODE: 0 none, 1 per-M', 2 per-N'.
// Split-K: blockIdx.z = batch*nsplit + s; k-window = [s*K, (s+1)*K).
// SPLITOUT: Z fp32 partial indexed by bz (plain stores, reducer sums slices).
// EXPSUM: epilogue writes exp(alpha*acc) (bf16) and atomically accumulates
//         per-n' row sums into rsum[bb*4096 + n'] (softmax denominators).
// ---------------------------------------------------------------------------
template<int BIAS_MODE, bool OUT_BF16, bool SPLITOUT, bool EXPSUM>
__global__ __launch_bounds__(256) void gemm_tn(
    const __hip_bfloat16* __restrict__ A, int lda, size_t sA,
    const __hip_bfloat16* __restrict__ B, int ldb, size_t sB,
    void* __restrict__ Zv, int ldz, size_t sZ,
    const float* __restrict__ bias,
    float alpha, int K, int nsplit,
    float* __restrict__ rsum)
{
  __shared__ __hip_bfloat16 lsA[128 * 32];
  __shared__ __hip_bfloat16 lsB[128 * 32];
  const int t    = threadIdx.x;
  const int bz   = blockIdx.z;
  const int bb   = bz / nsplit;          // batch index
  const int sp   = bz - bb * nsplit;     // split index
  const size_t koff = (size_t)sp * K;
  const int n0   = blockIdx.x * 128;
  const int m0   = blockIdx.y * 128;
  const __hip_bfloat16* Ab = A + (size_t)bb * sA + koff;
  const __hip_bfloat16* Bb = B + (size_t)bb * sB + koff;

  const int lane = t & 63;
  const int quad = lane >> 4;
  const int l16  = lane & 15;
  const int wave = t >> 6;
  const int wm   = (wave >> 1) * 64;
  const int wn   = (wave & 1) * 64;

  const int rowc = t >> 2;
  const int kc   = (t & 3) * 8;
  const __hip_bfloat16* ga0 = Ab + (size_t)(m0 + rowc) * lda + kc;
  const __hip_bfloat16* ga1 = Ab + (size_t)(m0 + rowc + 64) * lda + kc;
  const __hip_bfloat16* gb0 = Bb + (size_t)(n0 + rowc) * ldb + kc;
  const __hip_bfloat16* gb1 = Bb + (size_t)(n0 + rowc + 64) * ldb + kc;
  __hip_bfloat16* la0 = lsA + t * 8;
  __hip_bfloat16* la1 = lsA + 2048 + t * 8;
  __hip_bfloat16* lb0 = lsB + t * 8;
  __hip_bfloat16* lb1 = lsB + 2048 + t * 8;

  f32x4 acc[4][4] = {};

  for (int k0 = 0; k0 < K; k0 += 32) {
    __syncthreads();
    async_cp16(ga0, la0);
    async_cp16(ga1, la1);
    async_cp16(gb0, lb0);
    async_cp16(gb1, lb1);
    ga0 += 32; ga1 += 32; gb0 += 32; gb1 += 32;
    __syncthreads();

    short8 af[4], bf[4];
#pragma unroll
    for (int i = 0; i < 4; ++i)
      af[i] = *(const short8*)(lsA + (wm + i * 16 + l16) * 32 + quad * 8);
#pragma unroll
    for (int j = 0; j < 4; ++j)
      bf[j] = *(const short8*)(lsB + (wn + j * 16 + l16) * 32 + quad * 8);
#pragma unroll
    for (int i = 0; i < 4; ++i)
#pragma unroll
      for (int j = 0; j < 4; ++j)
        acc[i][j] = __builtin_amdgcn_mfma_f32_16x16x32_bf16(af[i], bf[j], acc[i][j], 0, 0, 0);
  }

  if (EXPSUM) {
    // p = exp(alpha*acc); row sums over m into rsum[n].
    __syncthreads();                       // all waves done with LDS tiles
    float* rs = (float*)lsA;               // 128 per-n partial sums
    if (t < 128) rs[t] = 0.f;
    __syncthreads();
    float lsum[4] = {0.f, 0.f, 0.f, 0.f};
#pragma unroll
    for (int i = 0; i < 4; ++i) {
#pragma unroll
      for (int j = 0; j < 4; ++j) {
        const int m = m0 + wm + i * 16 + quad * 4;
        const int n = n0 + wn + j * 16 + l16;
        f32x4 v = acc[i][j];
        v[0] = __expf(v[0] * alpha); v[1] = __expf(v[1] * alpha);
        v[2] = __expf(v[2] * alpha); v[3] = __expf(v[3] * alpha);
        lsum[j] += v[0] + v[1] + v[2] + v[3];
        union { u16 s[4]; uint2 q; } pk;
        pk.s[0] = f2bf(v[0]); pk.s[1] = f2bf(v[1]);
        pk.s[2] = f2bf(v[2]); pk.s[3] = f2bf(v[3]);
        *(uint2*)((__hip_bfloat16*)Zv + (size_t)bb * sZ + (size_t)n * ldz + m) = pk.q;
      }
    }
#pragma unroll
    for (int j = 0; j < 4; ++j)
      atomicAdd(&rs[wn + j * 16 + l16], lsum[j]);
    __syncthreads();
    if (t < 128) atomicAdd(rsum + (size_t)bb * 4096 + n0 + t, rs[t]);
    return;
  }

#pragma unroll
  for (int i = 0; i < 4; ++i) {
#pragma unroll
    for (int j = 0; j < 4; ++j) {
      const int m = m0 + wm + i * 16 + quad * 4;
      const int n = n0 + wn + j * 16 + l16;
      f32x4 v = acc[i][j];
      if (BIAS_MODE == 1) v += *(const f32x4*)(bias + m);
      else if (BIAS_MODE == 2) v += bias[n];
      v *= alpha;
      const size_t zoff = (size_t)n * ldz + m;
      if (SPLITOUT) {
        *(f32x4*)((float*)Zv + (size_t)bz * sZ + zoff) = v;
      } else if (OUT_BF16) {
        union { u16 s[4]; uint2 q; } pk;
        pk.s[0] = f2bf(v[0]); pk.s[1] = f2bf(v[1]);
        pk.s[2] = f2bf(v[2]); pk.s[3] = f2bf(v[3]);
        *(uint2*)((__hip_bfloat16*)Zv + (size_t)bb * sZ + zoff) = pk.q;
      } else {
        *(f32x4*)((float*)Zv + (size_t)bb * sZ + zoff) = v;
      }
    }
  }
}

// ---------------------------------------------------------------------------
__global__ __launch_bounds__(256) void gn_stats(const float* __restrict__ x,
                                                float2* __restrict__ stats) {
  const int bg = blockIdx.x;
  const f32x4* p = (const f32x4*)(x + (size_t)bg * 65536);
  float s = 0.f, s2 = 0.f;
  for (int i = threadIdx.x; i < 16384; i += 256) {
    f32x4 v = p[i];
    s  += v[0] + v[1] + v[2] + v[3];
    s2 += v[0]*v[0] + v[1]*v[1] + v[2]*v[2] + v[3]*v[3];
  }
  for (int o = 32; o > 0; o >>= 1) { s += __shfl_down(s, o); s2 += __shfl_down(s2, o); }
  __shared__ float ws[4], ws2[4];
  const int wave = threadIdx.x >> 6;
  if ((threadIdx.x & 63) == 0) { ws[wave] = s; ws2[wave] = s2; }
  __syncthreads();
  if (threadIdx.x == 0) {
    float S  = ws[0] + ws[1] + ws[2] + ws[3];
    float S2 = ws2[0] + ws2[1] + ws2[2] + ws2[3];
    float mu = S * (1.f / 65536.f);
    float var = S2 * (1.f / 65536.f) - mu * mu;
    stats[bg] = make_float2(mu, rsqrtf(var + 1e-6f));
  }
}

// GroupNorm apply + transpose: x[b][c][n] fp32 -> r_t[b][n][c] bf16.
__global__ __launch_bounds__(256) void gn_apply(const float* __restrict__ x,
                                                const float2* __restrict__ stats,
                                                const float* __restrict__ gamma,
                                                const float* __restrict__ beta,
                                                __hip_bfloat16* __restrict__ rt) {
  const int b = blockIdx.y, n0 = blockIdx.x * 64;
  __shared__ float tile[64][65];
  const int t  = threadIdx.x;
  const int cl = t >> 2;
  const int q4 = (t & 3) * 4;
  for (int cc = 0; cc < 8; ++cc) {
    const int c = cc * 64 + cl;
    const float2 ms = stats[b * 32 + (c >> 4)];
    const float ga = gamma[c] * ms.y;
    const float be = beta[c] - ms.x * ga;
    const float* src = x + ((size_t)b * 512 + c) * 4096 + n0;
#pragma unroll
    for (int p = 0; p < 4; ++p) {
      f32x4 v = *(const f32x4*)(src + q4 + p * 16);
      tile[cl][q4 + p * 16 + 0] = fmaf(v[0], ga, be);
      tile[cl][q4 + p * 16 + 1] = fmaf(v[1], ga, be);
      tile[cl][q4 + p * 16 + 2] = fmaf(v[2], ga, be);
      tile[cl][q4 + p * 16 + 3] = fmaf(v[3], ga, be);
    }
    __syncthreads();
    const int nw = t >> 2;
    const int cw = (t & 3) * 16;
    union { u16 s[16]; uint4 q[2]; } pk;
#pragma unroll
    for (int j = 0; j < 16; ++j) pk.s[j] = f2bf(tile[cw + j][nw]);
    __hip_bfloat16* dst = rt + ((size_t)b * 4096 + n0 + nw) * 512 + cc * 64 + cw;
    *(uint4*)dst = pk.q[0];
    *((uint4*)dst + 1) = pk.q[1];
    __syncthreads();
  }
}

__global__ __launch_bounds__(256) void cvt_bf16(const float* __restrict__ s,
                                                __hip_bfloat16* __restrict__ d, int n) {
  const int i = (blockIdx.x * 256 + threadIdx.x) * 4;
  if (i < n) {
    f32x4 v = *(const f32x4*)(s + i);
    union { u16 s4[4]; uint2 q; } pk;
    pk.s4[0] = f2bf(v[0]); pk.s4[1] = f2bf(v[1]);
    pk.s4[2] = f2bf(v[2]); pk.s4[3] = f2bf(v[3]);
    *(uint2*)(d + i) = pk.q;
  }
}

__global__ __launch_bounds__(256) void pack_bias(const float* __restrict__ qb,
                                                 const float* __restrict__ kb,
                                                 float* __restrict__ dst) {
  const int i = blockIdx.x * 256 + threadIdx.x;
  if (i < 512) dst[i] = qb[i];
  else if (i < 1024) dst[i] = kb[i - 512];
}

__global__ __launch_bounds__(256) void zero_f32(float* __restrict__ p) {
  ((f32x4*)p)[blockIdx.x * 256 + threadIdx.x] = f32x4{0.f, 0.f, 0.f, 0.f};
}

// out[b0+g][c][n] = x[...] + pb[c] + (sum_s part[g*S+s][c][n]) / rsum[g][n]
__global__ __launch_bounds__(256) void reduce_out(
    const float* __restrict__ part, const float* __restrict__ x,
    const float* __restrict__ pb, const float* __restrict__ rsum,
    float* __restrict__ out, int S, int b0) {
  constexpr size_t NC = (size_t)4096 * 512;
  const int g = blockIdx.y;
  const size_t r = ((size_t)blockIdx.x * 256 + threadIdx.x) * 4;
  const int c = (int)(r >> 12);          // r / 4096
  const int n = (int)(r & 4095);
  const float* ps = part + (size_t)g * S * NC + r;
  f32x4 acc = *(const f32x4*)(ps);
  for (int s = 1; s < S; ++s) acc += *(const f32x4*)(ps + (size_t)s * NC);
  f32x4 rs = *(const f32x4*)(rsum + (size_t)g * 4096 + n);
  f32x4 v = *(const f32x4*)(x + (size_t)(b0 + g) * NC + r);
  const float b = pb[c];
  v[0] += b + acc[0] / rs[0];
  v[1] += b + acc[1] / rs[1];
  v[2] += b + acc[2] / rs[2];
  v[3] += b + acc[3] / rs[3];
  *(f32x4*)(out + (size_t)(b0 + g) * NC + r) = v;
}

// ---------------------------------------------------------------------------
extern "C" void kernel_launch(void* const* d_in, const int* in_sizes, int n_in,
                              void* d_out, int out_size, void* d_ws, size_t ws_size,
                              hipStream_t stream) {
  const float* x     = (const float*)d_in[0];
  const float* gamma = (const float*)d_in[1];
  const float* beta  = (const float*)d_in[2];
  const float* q_w   = (const float*)d_in[3];
  const float* q_b   = (const float*)d_in[4];
  const float* k_w   = (const float*)d_in[5];
  const float* k_b   = (const float*)d_in[6];
  const float* p_w   = (const float*)d_in[7];
  const float* p_b   = (const float*)d_in[8];
  float* out = (float*)d_out;

  constexpr int B = 8, C = 512, N = 4096;
  constexpr size_t NC = (size_t)N * C;        // 2M elems per batch
  constexpr size_t NN = (size_t)N * N;        // 16M elems per batch attn

  char* ws = (char*)d_ws;
  size_t off = 0;
  auto alloc = [&](size_t bytes) {
    void* p = ws + off;
    off += (bytes + 255) & ~(size_t)255;
    return p;
  };

  __hip_bfloat16* wqk = (__hip_bfloat16*)alloc((size_t)1024 * 512 * 2); // [wq;wk]
  __hip_bfloat16* wp  = (__hip_bfloat16*)alloc((size_t)C * C * 2);
  float* bias_qk      = (float*)alloc(1024 * 4);
  float2* stats       = (float2*)alloc((size_t)B * 32 * sizeof(float2));
  float* rsum         = (float*)alloc((size_t)2 * N * 4);                 // per-chunk
  __hip_bfloat16* rt  = (__hip_bfloat16*)alloc(B * NC * 2);               // [b][n][c]
  __hip_bfloat16* qkt = (__hip_bfloat16*)alloc(B * (size_t)N * 1024 * 2); // [b][n][q|k]
  __hip_bfloat16* wpv = (__hip_bfloat16*)alloc(B * NC * 2);               // [b][o][m]
  float* part         = (float*)alloc((size_t)8 * NC * 4);                // 67 MB
  const size_t base_off = off;

  // chunking: G batches per iteration, split-K factor S with G*S == 8.
  // G=2 keeps the chunk working set (attn 67 MB + part 67 MB) inside L3.
  const size_t attn_b_bytes = NN * 2;
  size_t avail = (ws_size > base_off) ? ws_size - base_off : 0;
  int G = 2, S = 4;
  if (avail < 2 * attn_b_bytes) { G = 1; S = 8; }
  __hip_bfloat16* attn = (__hip_bfloat16*)alloc(attn_b_bytes * G);

  const dim3 blk(256);
  const float scale = 0.044194173824159216f;  // 512^-0.5 (alpha of QK^T)

  cvt_bf16<<<dim3(256), blk, 0, stream>>>(q_w, wqk, C * C);
  cvt_bf16<<<dim3(256), blk, 0, stream>>>(k_w, wqk + (size_t)C * C, C * C);
  cvt_bf16<<<dim3(256), blk, 0, stream>>>(p_w, wp, C * C);
  pack_bias<<<dim3(4), blk, 0, stream>>>(q_b, k_b, bias_qk);

  gn_stats<<<dim3(B * 32), blk, 0, stream>>>(x, stats);
  gn_apply<<<dim3(64, B), blk, 0, stream>>>(x, stats, gamma, beta, rt);

  // merged q|k projection: qkt[b][n][m'] (m'<512: q+qb, m'>=512: k+kb)
  gemm_tn<1, true, false, false><<<dim3(32, 8, B), blk, 0, stream>>>(
      wqk, C, 0, rt, C, NC, qkt, 1024, (size_t)N * 1024,
      bias_qk, 1.f, C, 1, nullptr);

  // wpv[b][o][m] = sum_c wp[o][c] * k_hat[m][c]   (V = k_hat, bias included)
  gemm_tn<0, true, false, false><<<dim3(4, 32, B), blk, 0, stream>>>(
      qkt + 512, 1024, (size_t)N * 1024, wp, C, 0,
      wpv, N, NC, nullptr, 1.f, C, 1, nullptr);

  for (int b0 = 0; b0 < B; ) {
    const int Gc = (B - b0 < G) ? (B - b0) : G;

    // rsum := 0 (Gc*4096 floats)
    zero_f32<<<dim3(Gc * N / 1024), blk, 0, stream>>>(rsum);

    // p[n][m] = exp(scale * sum_c k_hat[m][c] * q_hat[n][c]); rsum[n] += ...
    gemm_tn<0, true, false, true><<<dim3(32, 32, Gc), blk, 0, stream>>>(
        qkt + (size_t)b0 * N * 1024 + 512, 1024, (size_t)N * 1024,
        qkt + (size_t)b0 * N * 1024,       1024, (size_t)N * 1024,
        attn, N, NN, nullptr, scale, C, 1, rsum);

    // part[g*S+s][o][n] = sum_{m in split s} wpv[o][m] * p[n][m]
    gemm_tn<0, false, true, false><<<dim3(4, 32, Gc * S), blk, 0, stream>>>(
        attn, N, NN, wpv + (size_t)b0 * NC, N, NC,
        part, N, NC, nullptr, 1.f, N / S, S, nullptr);

    // out = x + pb + (sum_s part) / rsum
    reduce_out<<<dim3(2048, Gc), blk, 0, stream>>>(part, x, p_b, rsum, out, S, b0);
    b0 += Gc;
  }
}

// Round 6
// 1078.192 us; speedup vs baseline: 1.5213x; 1.0136x over previous
//
#include <hip/hip_runtime.h>
#include <hip/hip_bf16.h>
#include <cstdint>

#define DEVI __device__ __forceinline__

typedef __attribute__((ext_vector_type(8))) short short8;
typedef __attribute__((ext_vector_type(4))) float f32x4;
typedef unsigned int u32;
typedef unsigned short u16;

DEVI u16 f2bf(float f) {
  __hip_bfloat16 h = __float2bfloat16(f);
  return *reinterpret_cast<u16*>(&h);
}

// async global->LDS, 16B per lane. LDS dest must be wave-uniform base + lane*16.
DEVI void async_cp16(const __hip_bfloat16* g, __hip_bfloat16* l) {
  __builtin_amdgcn_global_load_lds(
      (const __attribute__((address_space(1))) u32*)(uintptr_t)g,
      (__attribute__((address_space(3))) u32*)(uintptr_t)l, 16, 0, 0);
}

// ---------------------------------------------------------------------------
// Generic TN GEMM: Z[n'][m'] = alpha * (sum_k A[m'][k]*B[n'][k] + bias)
// A: M x K (K contiguous, lda), B: N x K (ldb). bf16. Tile 128x128, BK=32.
// Z addr = n'*ldz + m'. BIAS_MODE: 0 none, 1 per-M', 2 per-N'.
// Split-K: blockIdx.z = batch*nsplit + s; k-window = [s*K, (s+1)*K).
// SPLITOUT: Z fp32 partial indexed by bz (plain stores, reducer sums slices).
// EXPSUM: epilogue writes exp(alpha*acc) (bf16) and atomically accumulates
//         per-n' row sums into rsum[bb*4096 + n'] (softmax denominators).
// ---------------------------------------------------------------------------
template<int BIAS_MODE, bool OUT_BF16, bool SPLITOUT, bool EXPSUM>
__global__ __launch_bounds__(256) void gemm_tn(
    const __hip_bfloat16* __restrict__ A, int lda, size_t sA,
    const __hip_bfloat16* __restrict__ B, int ldb, size_t sB,
    void* __restrict__ Zv, int ldz, size_t sZ,
    const float* __restrict__ bias,
    float alpha, int K, int nsplit,
    float* __restrict__ rsum)
{
  __shared__ __hip_bfloat16 lsA[128 * 32];
  __shared__ __hip_bfloat16 lsB[128 * 32];
  const int t    = threadIdx.x;
  const int bz   = blockIdx.z;
  const int bb   = bz / nsplit;          // batch index
  const int sp   = bz - bb * nsplit;     // split index
  const size_t koff = (size_t)sp * K;
  const int n0   = blockIdx.x * 128;
  const int m0   = blockIdx.y * 128;
  const __hip_bfloat16* Ab = A + (size_t)bb * sA + koff;
  const __hip_bfloat16* Bb = B + (size_t)bb * sB + koff;

  const int lane = t & 63;
  const int quad = lane >> 4;
  const int l16  = lane & 15;
  const int wave = t >> 6;
  const int wm   = (wave >> 1) * 64;
  const int wn   = (wave & 1) * 64;

  const int rowc = t >> 2;
  const int kc   = (t & 3) * 8;
  const __hip_bfloat16* ga0 = Ab + (size_t)(m0 + rowc) * lda + kc;
  const __hip_bfloat16* ga1 = Ab + (size_t)(m0 + rowc + 64) * lda + kc;
  const __hip_bfloat16* gb0 = Bb + (size_t)(n0 + rowc) * ldb + kc;
  const __hip_bfloat16* gb1 = Bb + (size_t)(n0 + rowc + 64) * ldb + kc;
  __hip_bfloat16* la0 = lsA + t * 8;
  __hip_bfloat16* la1 = lsA + 2048 + t * 8;
  __hip_bfloat16* lb0 = lsB + t * 8;
  __hip_bfloat16* lb1 = lsB + 2048 + t * 8;

  f32x4 acc[4][4] = {};

  for (int k0 = 0; k0 < K; k0 += 32) {
    __syncthreads();
    async_cp16(ga0, la0);
    async_cp16(ga1, la1);
    async_cp16(gb0, lb0);
    async_cp16(gb1, lb1);
    ga0 += 32; ga1 += 32; gb0 += 32; gb1 += 32;
    __syncthreads();

    short8 af[4], bf[4];
#pragma unroll
    for (int i = 0; i < 4; ++i)
      af[i] = *(const short8*)(lsA + (wm + i * 16 + l16) * 32 + quad * 8);
#pragma unroll
    for (int j = 0; j < 4; ++j)
      bf[j] = *(const short8*)(lsB + (wn + j * 16 + l16) * 32 + quad * 8);
#pragma unroll
    for (int i = 0; i < 4; ++i)
#pragma unroll
      for (int j = 0; j < 4; ++j)
        acc[i][j] = __builtin_amdgcn_mfma_f32_16x16x32_bf16(af[i], bf[j], acc[i][j], 0, 0, 0);
  }

  if (EXPSUM) {
    // p = exp(alpha*acc); row sums over m into rsum[n].
    __syncthreads();                       // all waves done with LDS tiles
    float* rs = (float*)lsA;               // 128 per-n partial sums
    if (t < 128) rs[t] = 0.f;
    __syncthreads();
    float lsum[4] = {0.f, 0.f, 0.f, 0.f};
#pragma unroll
    for (int i = 0; i < 4; ++i) {
#pragma unroll
      for (int j = 0; j < 4; ++j) {
        const int m = m0 + wm + i * 16 + quad * 4;
        const int n = n0 + wn + j * 16 + l16;
        f32x4 v = acc[i][j];
        v[0] = __expf(v[0] * alpha); v[1] = __expf(v[1] * alpha);
        v[2] = __expf(v[2] * alpha); v[3] = __expf(v[3] * alpha);
        lsum[j] += v[0] + v[1] + v[2] + v[3];
        union { u16 s[4]; uint2 q; } pk;
        pk.s[0] = f2bf(v[0]); pk.s[1] = f2bf(v[1]);
        pk.s[2] = f2bf(v[2]); pk.s[3] = f2bf(v[3]);
        *(uint2*)((__hip_bfloat16*)Zv + (size_t)bb * sZ + (size_t)n * ldz + m) = pk.q;
      }
    }
#pragma unroll
    for (int j = 0; j < 4; ++j)
      atomicAdd(&rs[wn + j * 16 + l16], lsum[j]);
    __syncthreads();
    if (t < 128) atomicAdd(rsum + (size_t)bb * 4096 + n0 + t, rs[t]);
    return;
  }

#pragma unroll
  for (int i = 0; i < 4; ++i) {
#pragma unroll
    for (int j = 0; j < 4; ++j) {
      const int m = m0 + wm + i * 16 + quad * 4;
      const int n = n0 + wn + j * 16 + l16;
      f32x4 v = acc[i][j];
      if (BIAS_MODE == 1) v += *(const f32x4*)(bias + m);
      else if (BIAS_MODE == 2) v += bias[n];
      v *= alpha;
      const size_t zoff = (size_t)n * ldz + m;
      if (SPLITOUT) {
        *(f32x4*)((float*)Zv + (size_t)bz * sZ + zoff) = v;
      } else if (OUT_BF16) {
        union { u16 s[4]; uint2 q; } pk;
        pk.s[0] = f2bf(v[0]); pk.s[1] = f2bf(v[1]);
        pk.s[2] = f2bf(v[2]); pk.s[3] = f2bf(v[3]);
        *(uint2*)((__hip_bfloat16*)Zv + (size_t)bb * sZ + zoff) = pk.q;
      } else {
        *(f32x4*)((float*)Zv + (size_t)bb * sZ + zoff) = v;
      }
    }
  }
}

// ---------------------------------------------------------------------------
__global__ __launch_bounds__(256) void gn_stats(const float* __restrict__ x,
                                                float2* __restrict__ stats) {
  const int bg = blockIdx.x;
  const f32x4* p = (const f32x4*)(x + (size_t)bg * 65536);
  float s = 0.f, s2 = 0.f;
  for (int i = threadIdx.x; i < 16384; i += 256) {
    f32x4 v = p[i];
    s  += v[0] + v[1] + v[2] + v[3];
    s2 += v[0]*v[0] + v[1]*v[1] + v[2]*v[2] + v[3]*v[3];
  }
  for (int o = 32; o > 0; o >>= 1) { s += __shfl_down(s, o); s2 += __shfl_down(s2, o); }
  __shared__ float ws[4], ws2[4];
  const int wave = threadIdx.x >> 6;
  if ((threadIdx.x & 63) == 0) { ws[wave] = s; ws2[wave] = s2; }
  __syncthreads();
  if (threadIdx.x == 0) {
    float S  = ws[0] + ws[1] + ws[2] + ws[3];
    float S2 = ws2[0] + ws2[1] + ws2[2] + ws2[3];
    float mu = S * (1.f / 65536.f);
    float var = S2 * (1.f / 65536.f) - mu * mu;
    stats[bg] = make_float2(mu, rsqrtf(var + 1e-6f));
  }
}

// GroupNorm apply + transpose: x[b][c][n] fp32 -> r_t[b][n][c] bf16.
__global__ __launch_bounds__(256) void gn_apply(const float* __restrict__ x,
                                                const float2* __restrict__ stats,
                                                const float* __restrict__ gamma,
                                                const float* __restrict__ beta,
                                                __hip_bfloat16* __restrict__ rt) {
  const int b = blockIdx.y, n0 = blockIdx.x * 64;
  __shared__ float tile[64][65];
  const int t  = threadIdx.x;
  const int cl = t >> 2;
  const int q4 = (t & 3) * 4;
  for (int cc = 0; cc < 8; ++cc) {
    const int c = cc * 64 + cl;
    const float2 ms = stats[b * 32 + (c >> 4)];
    const float ga = gamma[c] * ms.y;
    const float be = beta[c] - ms.x * ga;
    const float* src = x + ((size_t)b * 512 + c) * 4096 + n0;
#pragma unroll
    for (int p = 0; p < 4; ++p) {
      f32x4 v = *(const f32x4*)(src + q4 + p * 16);
      tile[cl][q4 + p * 16 + 0] = fmaf(v[0], ga, be);
      tile[cl][q4 + p * 16 + 1] = fmaf(v[1], ga, be);
      tile[cl][q4 + p * 16 + 2] = fmaf(v[2], ga, be);
      tile[cl][q4 + p * 16 + 3] = fmaf(v[3], ga, be);
    }
    __syncthreads();
    const int nw = t >> 2;
    const int cw = (t & 3) * 16;
    union { u16 s[16]; uint4 q[2]; } pk;
#pragma unroll
    for (int j = 0; j < 16; ++j) pk.s[j] = f2bf(tile[cw + j][nw]);
    __hip_bfloat16* dst = rt + ((size_t)b * 4096 + n0 + nw) * 512 + cc * 64 + cw;
    *(uint4*)dst = pk.q[0];
    *((uint4*)dst + 1) = pk.q[1];
    __syncthreads();
  }
}

// One prep kernel: 3 weight casts + bias packing + rsum zeroing.
// grid 801 blocks: [0,256) qw->wqk, [256,512) kw->wqk+CC, [512,768) pw->wp,
// 768: bias pack, [769,801): zero rsum (8*4096 floats).
__global__ __launch_bounds__(256) void prep(
    const float* __restrict__ qw, const float* __restrict__ kw,
    const float* __restrict__ pw, const float* __restrict__ qb,
    const float* __restrict__ kb,
    __hip_bfloat16* __restrict__ wqk, __hip_bfloat16* __restrict__ wp,
    float* __restrict__ bias_qk, float* __restrict__ rsum) {
  const int blk = blockIdx.x;
  if (blk < 768) {
    const float* src = (blk < 256) ? qw : (blk < 512) ? kw : pw;
    __hip_bfloat16* dst = (blk < 256) ? wqk : (blk < 512) ? (wqk + 262144) : wp;
    const int i = ((blk & 255) * 256 + threadIdx.x) * 4;
    f32x4 v = *(const f32x4*)(src + i);
    union { u16 s4[4]; uint2 q; } pk;
    pk.s4[0] = f2bf(v[0]); pk.s4[1] = f2bf(v[1]);
    pk.s4[2] = f2bf(v[2]); pk.s4[3] = f2bf(v[3]);
    *(uint2*)(dst + i) = pk.q;
  } else if (blk == 768) {
    const int i = threadIdx.x * 4;
    *(f32x4*)(bias_qk + i) = *(const f32x4*)(qb + i);
    *(f32x4*)(bias_qk + 512 + i) = *(const f32x4*)(kb + i);
  } else {
    ((f32x4*)rsum)[(blk - 769) * 256 + threadIdx.x] = f32x4{0.f, 0.f, 0.f, 0.f};
  }
}

// out[b0+g][c][n] = x[...] + pb[c] + (sum_s part[g*S+s][c][n]) / rsum[b0+g][n]
__global__ __launch_bounds__(256) void reduce_out(
    const float* __restrict__ part, const float* __restrict__ x,
    const float* __restrict__ pb, const float* __restrict__ rsum,
    float* __restrict__ out, int S, int b0) {
  constexpr size_t NC = (size_t)4096 * 512;
  const int g = blockIdx.y;
  const size_t r = ((size_t)blockIdx.x * 256 + threadIdx.x) * 4;
  const int c = (int)(r >> 12);          // r / 4096
  const int n = (int)(r & 4095);
  const float* ps = part + (size_t)g * S * NC + r;
  f32x4 acc = *(const f32x4*)(ps);
  for (int s = 1; s < S; ++s) acc += *(const f32x4*)(ps + (size_t)s * NC);
  f32x4 rs = *(const f32x4*)(rsum + (size_t)(b0 + g) * 4096 + n);
  f32x4 v = *(const f32x4*)(x + (size_t)(b0 + g) * NC + r);
  const float b = pb[c];
  v[0] += b + acc[0] / rs[0];
  v[1] += b + acc[1] / rs[1];
  v[2] += b + acc[2] / rs[2];
  v[3] += b + acc[3] / rs[3];
  *(f32x4*)(out + (size_t)(b0 + g) * NC + r) = v;
}

// ---------------------------------------------------------------------------
extern "C" void kernel_launch(void* const* d_in, const int* in_sizes, int n_in,
                              void* d_out, int out_size, void* d_ws, size_t ws_size,
                              hipStream_t stream) {
  const float* x     = (const float*)d_in[0];
  const float* gamma = (const float*)d_in[1];
  const float* beta  = (const float*)d_in[2];
  const float* q_w   = (const float*)d_in[3];
  const float* q_b   = (const float*)d_in[4];
  const float* k_w   = (const float*)d_in[5];
  const float* k_b   = (const float*)d_in[6];
  const float* p_w   = (const float*)d_in[7];
  const float* p_b   = (const float*)d_in[8];
  float* out = (float*)d_out;

  constexpr int B = 8, C = 512, N = 4096;
  constexpr size_t NC = (size_t)N * C;        // 2M elems per batch
  constexpr size_t NN = (size_t)N * N;        // 16M elems per batch attn

  char* ws = (char*)d_ws;
  size_t off = 0;
  auto alloc = [&](size_t bytes) {
    void* p = ws + off;
    off += (bytes + 255) & ~(size_t)255;
    return p;
  };

  __hip_bfloat16* wqk = (__hip_bfloat16*)alloc((size_t)1024 * 512 * 2); // [wq;wk]
  __hip_bfloat16* wp  = (__hip_bfloat16*)alloc((size_t)C * C * 2);
  float* bias_qk      = (float*)alloc(1024 * 4);
  float2* stats       = (float2*)alloc((size_t)B * 32 * sizeof(float2));
  float* rsum         = (float*)alloc((size_t)B * N * 4);                 // all batches
  __hip_bfloat16* rt  = (__hip_bfloat16*)alloc(B * NC * 2);               // [b][n][c]
  __hip_bfloat16* qkt = (__hip_bfloat16*)alloc(B * (size_t)N * 1024 * 2); // [b][n][q|k]
  __hip_bfloat16* wpv = (__hip_bfloat16*)alloc(B * NC * 2);               // [b][o][m]
  float* part         = (float*)alloc((size_t)8 * NC * 4);                // 67 MB
  const size_t base_off = off;

  // chunking: G batches per iteration, split-K factor S with G*S == 8.
  // G=4: attn 134 MB + part 64 MB stays inside the 256 MB L3; 2 chunk iters.
  const size_t attn_b_bytes = NN * 2;
  size_t avail = (ws_size > base_off) ? ws_size - base_off : 0;
  int G = 4, S = 2;
  if (avail < 4 * attn_b_bytes) { G = 2; S = 4; }
  if (avail < 2 * attn_b_bytes) { G = 1; S = 8; }
  __hip_bfloat16* attn = (__hip_bfloat16*)alloc(attn_b_bytes * G);

  const dim3 blk(256);
  const float scale = 0.044194173824159216f;  // 512^-0.5 (alpha of QK^T)

  prep<<<dim3(801), blk, 0, stream>>>(q_w, k_w, p_w, q_b, k_b,
                                      wqk, wp, bias_qk, rsum);

  gn_stats<<<dim3(B * 32), blk, 0, stream>>>(x, stats);
  gn_apply<<<dim3(64, B), blk, 0, stream>>>(x, stats, gamma, beta, rt);

  // merged q|k projection: qkt[b][n][m'] (m'<512: q+qb, m'>=512: k+kb)
  gemm_tn<1, true, false, false><<<dim3(32, 8, B), blk, 0, stream>>>(
      wqk, C, 0, rt, C, NC, qkt, 1024, (size_t)N * 1024,
      bias_qk, 1.f, C, 1, nullptr);

  // wpv[b][o][m] = sum_c wp[o][c] * k_hat[m][c]   (V = k_hat, bias included)
  gemm_tn<0, true, false, false><<<dim3(4, 32, B), blk, 0, stream>>>(
      qkt + 512, 1024, (size_t)N * 1024, wp, C, 0,
      wpv, N, NC, nullptr, 1.f, C, 1, nullptr);

  for (int b0 = 0; b0 < B; ) {
    const int Gc = (B - b0 < G) ? (B - b0) : G;

    // p[n][m] = exp(scale * sum_c k_hat[m][c] * q_hat[n][c]); rsum[n] += ...
    gemm_tn<0, true, false, true><<<dim3(32, 32, Gc), blk, 0, stream>>>(
        qkt + (size_t)b0 * N * 1024 + 512, 1024, (size_t)N * 1024,
        qkt + (size_t)b0 * N * 1024,       1024, (size_t)N * 1024,
        attn, N, NN, nullptr, scale, C, 1, rsum + (size_t)b0 * N);

    // part[g*S+s][o][n] = sum_{m in split s} wpv[o][m] * p[n][m]
    gemm_tn<0, false, true, false><<<dim3(4, 32, Gc * S), blk, 0, stream>>>(
        attn, N, NN, wpv + (size_t)b0 * NC, N, NC,
        part, N, NC, nullptr, 1.f, N / S, S, nullptr);

    // out = x + pb + (sum_s part) / rsum
    reduce_out<<<dim3(2048, Gc), blk, 0, stream>>>(part, x, p_b, rsum, out, S, b0);
    b0 += Gc;
  }
}